// Round 10
// baseline (693.082 us; speedup 1.0000x reference)
//
#include <hip/hip_runtime.h>
#include <hip/hip_cooperative_groups.h>
namespace cg = cooperative_groups;

constexpr int N  = 100000;
constexpr int E  = 1600000;
constexpr int IN = 128, HID = 64, OUTC = 32;

constexpr int SHIFT = 8;                       // 256 nodes per bucket
constexpr int NPB   = 1 << SHIFT;              // 256
constexpr int NB    = (N + NPB - 1) / NPB;     // 391 buckets
constexpr int NBP   = 392;                     // padded stride
constexpr int GRID  = 512;
constexpr int TPB   = 512;
constexpr int CHUNK = E / GRID;                // 3125 exact
constexpr int CAP   = 6144;                    // bucket mean 4096, sigma~64

// ---- bf16 helpers ----
__device__ __forceinline__ unsigned short f2bf(float f) {
    union { float f; unsigned int u; } v; v.f = f;
    unsigned int u = v.u;
    return (unsigned short)((u + 0x7fffu + ((u >> 16) & 1u)) >> 16);
}
__device__ __forceinline__ float blo(unsigned u) { return __uint_as_float(u << 16); }
__device__ __forceinline__ float bhi(unsigned u) { return __uint_as_float(u & 0xffff0000u); }

__global__ __launch_bounds__(512, 4) void k_mega(
    const float* __restrict__ X,
    const int* __restrict__ src,
    const int* __restrict__ dst,
    const float* __restrict__ W1,
    const float* __restrict__ b1,
    const float* __restrict__ W2,
    const float* __restrict__ b2,
    float* __restrict__ out,
    int* __restrict__ hb,        // [GRID][NBP] per-block bucket counts
    int* __restrict__ obase,     // [GRID][NBP] per-block exclusive offsets
    int* __restrict__ colsum,    // [NB]
    int* __restrict__ bbase,     // [NB+1]
    int* __restrict__ offs,      // [N+1]
    float* __restrict__ dinv,    // [N]
    unsigned* __restrict__ packed, // [E] -> becomes csr in place
    unsigned short* __restrict__ Hs, // [N][HID] bf16, pre-scaled by dinv
    unsigned* __restrict__ H2u)      // [N][OUTC/2] bf16 pairs, pre-scaled
{
    cg::grid_group grid = cg::this_grid();
    __shared__ __align__(16) char smem[50176];   // union; max = gemm1 phase 49.7KB
    const int t = threadIdx.x, bid = blockIdx.x;

    // ---- phase 0: per-block bucket histogram (no global atomics, no memset) ----
    {
        int* lh = (int*)smem;
        for (int i = t; i < NB; i += TPB) lh[i] = 0;
        __syncthreads();
        const int beg = bid * CHUNK, end = beg + CHUNK;
        for (int e = beg + t; e < end; e += TPB) atomicAdd(&lh[dst[e] >> SHIFT], 1);
        __syncthreads();
        for (int i = t; i < NB; i += TPB) hb[bid * NBP + i] = lh[i];
    }
    grid.sync();

    // ---- phase 1: per-bucket exclusive scan over the 512 blocks ----
    if (bid < NB) {
        int* sb = (int*)smem;
        int v = hb[t * NBP + bid];
        sb[t] = v; __syncthreads();
        for (int off = 1; off < TPB; off <<= 1) {
            int x = (t >= off) ? sb[t - off] : 0;
            __syncthreads();
            sb[t] += x;
            __syncthreads();
        }
        obase[t * NBP + bid] = sb[t] - v;
        if (t == TPB - 1) colsum[bid] = sb[t];
    }
    grid.sync();

    // ---- phase 2: scan bucket totals -> bases ----
    if (bid == 0) {
        int* sb = (int*)smem;
        int v = (t < NB) ? colsum[t] : 0;
        sb[t] = v; __syncthreads();
        for (int off = 1; off < TPB; off <<= 1) {
            int x = (t >= off) ? sb[t - off] : 0;
            __syncthreads();
            sb[t] += x;
            __syncthreads();
        }
        if (t < NB) bbase[t] = sb[t] - v;
        if (t == 0) bbase[NB] = E;
    }
    grid.sync();

    // ---- phase 3: scatter edges into buckets (exact reservations, no global atomics) ----
    {
        int* lb = (int*)smem;           // [NB]
        int* lc = (int*)smem + NBP;     // [NB]
        for (int i = t; i < NB; i += TPB) {
            lb[i] = bbase[i] + obase[bid * NBP + i];
            lc[i] = 0;
        }
        __syncthreads();
        const int beg = bid * CHUNK, end = beg + CHUNK;
        for (int e = beg + t; e < end; e += TPB) {
            int d = dst[e], bkt = d >> SHIFT;
            int idx = atomicAdd(&lc[bkt], 1);
            packed[lb[bkt] + idx] = ((unsigned)(d & (NPB - 1)) << 17) | (unsigned)src[e];
        }
    }
    grid.sync();

    // ---- phase 4: per-bucket CSR build (offs + dinv + in-place sort) ----
    if (bid < NB) {
        int* cnt = (int*)smem;                           // [NPB]
        unsigned* stage = (unsigned*)((int*)smem + NPB); // [CAP] 24KB
        const int base = bbase[bid], cntE = bbase[bid + 1] - base;
        const int node0 = bid << SHIFT;
        if (t < NPB) cnt[t] = 0;
        __syncthreads();
        for (int i = t; i < cntE; i += TPB) atomicAdd(&cnt[packed[base + i] >> 17], 1);
        __syncthreads();
        int v = (t < NPB) ? cnt[t] : 0;
        __syncthreads();
        for (int off = 1; off < NPB; off <<= 1) {
            int x = (t < NPB && t >= off) ? cnt[t - off] : 0;
            __syncthreads();
            if (t < NPB) cnt[t] += x;
            __syncthreads();
        }
        if (t < NPB) {
            int node = node0 + t;
            if (node < N) {
                offs[node] = base + (cnt[t] - v);
                dinv[node] = rsqrtf((float)v + 1.0f);    // +1 self loop
            }
        }
        if (bid == 0 && t == 0) offs[N] = E;
        __syncthreads();
        if (t < NPB) cnt[t] -= v;                        // exclusive cursor
        __syncthreads();
        for (int i = t; i < cntE; i += TPB) {
            unsigned p = packed[base + i];
            int idx = atomicAdd(&cnt[p >> 17], 1);
            if (idx < CAP) stage[idx] = p & 0x1FFFFu;
        }
        __syncthreads();
        for (int i = t; i < cntE; i += TPB)
            packed[base + i] = stage[i];                 // in place: csr == packed
    }
    grid.sync();

    // ---- phase 5: gemm1  Hs = bf16(dinv[row] * (X @ W1)) ----
    {
        float* ws = (float*)smem;          // [IN*HID] 32KB
        float* xs = ws + IN * HID;         // [32*(IN+4)] 16.9KB
        for (int i = t; i < IN * HID / 4; i += TPB)
            ((float4*)ws)[i] = ((const float4*)W1)[i];
        __syncthreads();
        const int col0 = (t & 15) * 4, r = t >> 4;       // 32 rows x 16 colgroups
        for (int vb = bid; vb < N / 32; vb += GRID) {
            const int row0 = vb * 32;
            for (int i = t; i < 32 * IN / 4; i += TPB) {
                int rr = i >> 5, k4 = i & 31;
                *(float4*)&xs[rr * (IN + 4) + k4 * 4] =
                    ((const float4*)(X + (size_t)(row0 + rr) * IN))[k4];
            }
            __syncthreads();
            float4 a = {0, 0, 0, 0};
            for (int k = 0; k < IN; ++k) {
                float4 w = *(const float4*)&ws[k * HID + col0];
                float x = xs[r * (IN + 4) + k];
                a.x += x * w.x; a.y += x * w.y; a.z += x * w.z; a.w += x * w.w;
            }
            const float d = dinv[row0 + r];
            ushort4 p = {f2bf(a.x * d), f2bf(a.y * d), f2bf(a.z * d), f2bf(a.w * d)};
            *(ushort4*)(Hs + (size_t)(row0 + r) * HID + col0) = p;
            __syncthreads();
        }
    }
    grid.sync();

    // ---- phase 6: gather1 (half-wave/edge, dword/lane) + FUSED gemm2 ----
    {
        float* w2s  = (float*)smem;                    // [HID*OUTC] 8KB
        int*   sidx = (int*)(smem + 8192);             // [8][64] 2KB
        float* wrow = (float*)(smem + 8192 + 2048);    // [8][64] 2KB
        ((float4*)w2s)[t] = ((const float4*)W2)[t];    // 2048 floats
        __syncthreads();
        const int wave = t >> 6, lane = t & 63, c2 = lane & 31, half = lane >> 5;
        const unsigned* Hu = (const unsigned*)Hs;      // row stride 32 dwords
        const int* csr = (const int*)packed;
        for (int g = bid; g < N / 8; g += GRID) {
            const int node = g * 8 + wave;
            const int beg = offs[node], end = offs[node + 1];
            float ax0 = 0, ay0 = 0, ax1 = 0, ay1 = 0, ax2 = 0, ay2 = 0, ax3 = 0, ay3 = 0;
            if (half == 0) {                           // self loop (pre-scaled)
                unsigned u = Hu[(size_t)node * 32 + c2];
                ax0 = blo(u); ay0 = bhi(u);
            }
            for (int base = beg; base < end; base += 64) {
                const int n = min(64, end - base);
                if (lane < n) sidx[wave * 64 + lane] = csr[base + lane];
                int k = 0;
                for (; k + 7 < n; k += 8) {
                    int s0 = sidx[wave * 64 + k + half];
                    int s1 = sidx[wave * 64 + k + 2 + half];
                    int s2 = sidx[wave * 64 + k + 4 + half];
                    int s3 = sidx[wave * 64 + k + 6 + half];
                    unsigned u0 = Hu[(size_t)s0 * 32 + c2];
                    unsigned u1 = Hu[(size_t)s1 * 32 + c2];
                    unsigned u2 = Hu[(size_t)s2 * 32 + c2];
                    unsigned u3 = Hu[(size_t)s3 * 32 + c2];
                    ax0 += blo(u0); ay0 += bhi(u0);
                    ax1 += blo(u1); ay1 += bhi(u1);
                    ax2 += blo(u2); ay2 += bhi(u2);
                    ax3 += blo(u3); ay3 += bhi(u3);
                }
                for (; k + 1 < n; k += 2) {
                    int s = sidx[wave * 64 + k + half];
                    unsigned u = Hu[(size_t)s * 32 + c2];
                    ax0 += blo(u); ay0 += bhi(u);
                }
                if (k < n && half == 0) {
                    int s = sidx[wave * 64 + k];
                    unsigned u = Hu[(size_t)s * 32 + c2];
                    ax1 += blo(u); ay1 += bhi(u);
                }
            }
            float sx = (ax0 + ax1) + (ax2 + ax3);
            float sy = (ay0 + ay1) + (ay2 + ay3);
            sx += __shfl_down(sx, 32, 64);
            sy += __shfl_down(sy, 32, 64);
            const float dn = dinv[node];
            if (half == 0) {                           // O1 row -> LDS (relu+bias fused)
                float2 bb = *(const float2*)(b1 + 2 * c2);
                wrow[wave * 64 + 2 * c2]     = fmaxf(sx * dn + bb.x, 0.0f);
                wrow[wave * 64 + 2 * c2 + 1] = fmaxf(sy * dn + bb.y, 0.0f);
            }
            // fused gemm2: H2[ch] = dinv * sum_k wrow[k]*W2[k][ch]; k split by half
            const int ch = lane & 31;
            float acc = 0.0f;
            #pragma unroll 8
            for (int k = 0; k < 32; ++k) {
                float xv = wrow[wave * 64 + half * 32 + k];      // broadcast
                acc += xv * w2s[(half * 32 + k) * 32 + ch];
            }
            acc += __shfl_down(acc, 32, 64);
            float hval = acc * dn;
            unsigned short me = f2bf(hval);
            float hpart = __shfl_down(hval, 1, 64);
            if (half == 0 && (lane & 1) == 0)
                H2u[(size_t)node * 16 + (lane >> 1)] =
                    (unsigned)me | ((unsigned)f2bf(hpart) << 16);
        }
    }
    grid.sync();

    // ---- phase 7: gather2 (quarter-wave/edge, dword/lane) ----
    {
        int* sidx = (int*)smem;
        const int wave = t >> 6, lane = t & 63, c2 = lane & 15, q = lane >> 4;
        const int* csr = (const int*)packed;
        for (int g = bid; g < N / 8; g += GRID) {
            const int node = g * 8 + wave;
            const int beg = offs[node], end = offs[node + 1];
            float ax0 = 0, ay0 = 0, ax1 = 0, ay1 = 0;
            if (q == 0) {                              // self loop
                unsigned u = H2u[(size_t)node * 16 + c2];
                ax0 = blo(u); ay0 = bhi(u);
            }
            for (int base = beg; base < end; base += 64) {
                const int n = min(64, end - base);
                if (lane < n) sidx[wave * 64 + lane] = csr[base + lane];
                int k = 0;
                for (; k + 7 < n; k += 8) {
                    int s0 = sidx[wave * 64 + k + q];
                    int s1 = sidx[wave * 64 + k + 4 + q];
                    unsigned u0 = H2u[(size_t)s0 * 16 + c2];
                    unsigned u1 = H2u[(size_t)s1 * 16 + c2];
                    ax0 += blo(u0); ay0 += bhi(u0);
                    ax1 += blo(u1); ay1 += bhi(u1);
                }
                for (; k < n; k += 4) {
                    if (k + q < n) {
                        int s = sidx[wave * 64 + k + q];
                        unsigned u = H2u[(size_t)s * 16 + c2];
                        ax1 += blo(u); ay1 += bhi(u);
                    }
                }
            }
            float sx = ax0 + ax1, sy = ay0 + ay1;
            sx += __shfl_down(sx, 32, 64); sy += __shfl_down(sy, 32, 64);
            sx += __shfl_down(sx, 16, 64); sy += __shfl_down(sy, 16, 64);
            if (q == 0) {
                float dn = dinv[node];
                float2 bb = *(const float2*)(b2 + 2 * c2);
                float2 r;
                r.x = sx * dn + bb.x;
                r.y = sy * dn + bb.y;
                *(float2*)(out + (size_t)node * OUTC + 2 * c2) = r;
            }
        }
    }
}

extern "C" void kernel_launch(void* const* d_in, const int* in_sizes, int n_in,
                              void* d_out, int out_size, void* d_ws, size_t ws_size,
                              hipStream_t stream) {
    const float* x   = (const float*)d_in[0];
    const int*   ei  = (const int*)d_in[1];
    const float* W1  = (const float*)d_in[2];
    const float* b1  = (const float*)d_in[3];
    const float* W2  = (const float*)d_in[4];
    const float* b2  = (const float*)d_in[5];
    float*       out = (float*)d_out;

    const int* srcp = ei;
    const int* dstp = ei + E;

    char* ws = (char*)d_ws;
    int*            hb     = (int*)(ws + 0x0);         // 512*392*4 = 802816
    int*            obase  = (int*)(ws + 0xC4000);     // 802816
    int*            colsum = (int*)(ws + 0x188000);    // 1564
    int*            bbase  = (int*)(ws + 0x189000);    // 1568
    int*            offs   = (int*)(ws + 0x18A000);    // 400004
    float*          dinv   = (float*)(ws + 0x1F0000);  // 400000
    unsigned*       packed = (unsigned*)(ws + 0x260000);       // 6.4 MB
    unsigned short* Hs     = (unsigned short*)(ws + 0x900000); // 12.8 MB
    unsigned*       H2u    = (unsigned*)(ws + 0x1600000);      // 6.4 MB -> ends ~29.5 MB

    void* args[] = {
        (void*)&x, (void*)&srcp, (void*)&dstp, (void*)&W1, (void*)&b1,
        (void*)&W2, (void*)&b2, (void*)&out, (void*)&hb, (void*)&obase,
        (void*)&colsum, (void*)&bbase, (void*)&offs, (void*)&dinv,
        (void*)&packed, (void*)&Hs, (void*)&H2u
    };
    hipLaunchCooperativeKernel((void*)k_mega, dim3(GRID), dim3(TPB), args, 0, stream);
}

// Round 11
// 247.362 us; speedup vs baseline: 2.8019x; 2.8019x over previous
//
#include <hip/hip_runtime.h>

constexpr int N  = 100000;
constexpr int E  = 1600000;
constexpr int IN = 128, HID = 64, OUTC = 32;

// coarse radix partition params (R6-proven)
constexpr int SHIFT = 9;                       // 512 nodes per bucket
constexpr int NPB   = 1 << SHIFT;              // 512
constexpr int NB    = (N + NPB - 1) / NPB;     // 196 buckets
constexpr int CAP   = 16384;                   // LDS stage cap (mean 8163, sigma~90)
constexpr int PB    = 256;                     // partition blocks
constexpr int CHUNK = E / PB;                  // 6250 (exact)

// ---- bf16 helpers ----
__device__ __forceinline__ unsigned short f2bf(float f) {
    union { float f; unsigned int u; } v; v.f = f;
    unsigned int u = v.u;
    return (unsigned short)((u + 0x7fffu + ((u >> 16) & 1u)) >> 16);
}
__device__ __forceinline__ float blo(unsigned u) { return __uint_as_float(u << 16); }
__device__ __forceinline__ float bhi(unsigned u) { return __uint_as_float(u & 0xffff0000u); }

// ---------------- coarse histogram ----------------
__global__ __launch_bounds__(256) void k_hist(const int* __restrict__ dst,
                                              int* __restrict__ gcnt) {
    __shared__ int h[NB];
    for (int i = threadIdx.x; i < NB; i += 256) h[i] = 0;
    __syncthreads();
    const int tid = blockIdx.x * 256 + threadIdx.x, nt = gridDim.x * 256;
    for (int e = tid; e < E; e += nt) atomicAdd(&h[dst[e] >> SHIFT], 1);
    __syncthreads();
    for (int i = threadIdx.x; i < NB; i += 256)
        if (h[i]) atomicAdd(&gcnt[i], h[i]);
}

// ---------------- scan 196 bucket totals ----------------
__global__ void k_bscan(const int* __restrict__ gcnt, int* __restrict__ base,
                        int* __restrict__ cursor) {
    __shared__ int sb[256];
    const int t = threadIdx.x;
    int v = (t < NB) ? gcnt[t] : 0;
    sb[t] = v; __syncthreads();
    for (int off = 1; off < 256; off <<= 1) {
        int x = (t >= off) ? sb[t - off] : 0;
        __syncthreads();
        sb[t] += x;
        __syncthreads();
    }
    if (t < NB) { int ex = sb[t] - v; base[t] = ex; cursor[t] = ex; }
    if (t == 0) base[NB] = E;
}

// ---------------- partition edges into coarse buckets ----------------
__global__ __launch_bounds__(256) void k_part(const int* __restrict__ src,
                                              const int* __restrict__ dst,
                                              int* __restrict__ cursor,
                                              unsigned* __restrict__ packed) {
    __shared__ int lh[NB], lb[NB], lc[NB];
    const int t = threadIdx.x;
    const int beg = blockIdx.x * CHUNK, end = beg + CHUNK;
    for (int i = t; i < NB; i += 256) lh[i] = 0;
    __syncthreads();
    for (int e = beg + t; e < end; e += 256) atomicAdd(&lh[dst[e] >> SHIFT], 1);
    __syncthreads();
    for (int i = t; i < NB; i += 256) {
        lb[i] = lh[i] ? atomicAdd(&cursor[i], lh[i]) : 0;
        lc[i] = 0;
    }
    __syncthreads();
    for (int e = beg + t; e < end; e += 256) {
        int d = dst[e], b = d >> SHIFT;
        int idx = atomicAdd(&lc[b], 1);
        packed[lb[b] + idx] = ((unsigned)(d & (NPB - 1)) << 17) | (unsigned)src[e];
    }
}

// ---------------- per-bucket CSR build: offs + dinv + in-place sorted csr ----------------
__global__ __launch_bounds__(512) void k_build(const int* __restrict__ bbase,
                                               unsigned* __restrict__ packed,
                                               int* __restrict__ offs,
                                               float* __restrict__ dinv) {
    __shared__ int cnt[NPB];
    __shared__ unsigned stage[CAP];            // 64 KB
    const int t = threadIdx.x, b = blockIdx.x;
    const int base = bbase[b], cntE = bbase[b + 1] - base;
    const int node0 = b << SHIFT;
    cnt[t] = 0;
    __syncthreads();
    for (int i = t; i < cntE; i += 512) atomicAdd(&cnt[packed[base + i] >> 17], 1);
    __syncthreads();
    const int v = cnt[t];
    __syncthreads();
    for (int off = 1; off < NPB; off <<= 1) {
        int x = (t >= off) ? cnt[t - off] : 0;
        __syncthreads();
        cnt[t] += x;
        __syncthreads();
    }
    const int ex = cnt[t] - v;
    const int node = node0 + t;
    if (node < N) {
        offs[node] = base + ex;
        dinv[node] = rsqrtf((float)v + 1.0f);  // +1 self loop
    }
    if (node == N) offs[N] = E;
    __syncthreads();
    cnt[t] = ex;
    __syncthreads();
    for (int i = t; i < cntE; i += 512) {
        unsigned p = packed[base + i];
        int idx = atomicAdd(&cnt[p >> 17], 1);
        if (idx < CAP) stage[idx] = p & 0x1FFFFu;
    }
    __syncthreads();
    for (int i = t; i < cntE; i += 512)
        packed[base + i] = stage[i];           // in-place: csr == packed buffer
}

// ---------------- GEMM1: Hs = bf16(dinv[row] * (X @ W1)) ----------------
__global__ __launch_bounds__(256) void k_gemm1(const float* __restrict__ X,
                                               const float* __restrict__ W,
                                               const float* __restrict__ dinv,
                                               unsigned short* __restrict__ Hs) {
    constexpr int R  = 32;
    constexpr int XS = IN + 4;
    __shared__ float ws[IN * HID];             // 32 KB
    __shared__ float xs[R * XS];
    const int t    = threadIdx.x;
    const int row0 = blockIdx.x * R;

    for (int i = t; i < IN * HID / 4; i += 256)
        ((float4*)ws)[i] = ((const float4*)W)[i];
    for (int i = t; i < R * IN / 4; i += 256) {
        int r = i / (IN / 4), k4 = i % (IN / 4);
        *(float4*)&xs[r * XS + k4 * 4] =
            ((const float4*)(X + (size_t)(row0 + r) * IN))[k4];
    }
    __syncthreads();

    const int col0 = (t & 15) * 4;
    const int r0   = (t >> 4) * 2;
    float4 a0 = {0, 0, 0, 0}, a1 = {0, 0, 0, 0};
    for (int k = 0; k < IN; ++k) {
        float4 w = *(const float4*)&ws[k * HID + col0];
        float x0 = xs[r0 * XS + k];
        float x1 = xs[(r0 + 1) * XS + k];
        a0.x += x0 * w.x; a0.y += x0 * w.y; a0.z += x0 * w.z; a0.w += x0 * w.w;
        a1.x += x1 * w.x; a1.y += x1 * w.y; a1.z += x1 * w.z; a1.w += x1 * w.w;
    }
    const float d0 = dinv[row0 + r0];
    const float d1 = dinv[row0 + r0 + 1];
    ushort4 p0 = {f2bf(a0.x * d0), f2bf(a0.y * d0), f2bf(a0.z * d0), f2bf(a0.w * d0)};
    ushort4 p1 = {f2bf(a1.x * d1), f2bf(a1.y * d1), f2bf(a1.z * d1), f2bf(a1.w * d1)};
    *(ushort4*)(Hs + (size_t)(row0 + r0) * HID + col0)       = p0;
    *(ushort4*)(Hs + (size_t)(row0 + r0 + 1) * HID + col0)   = p1;
}

// ---------------- gather1 + fused gemm2 ----------------
// Each HALF-WAVE owns one node (2 adjacent nodes per wave -> contiguous csr
// range, shared staging, both halves gather in the SAME instructions = 2x
// node-level MLP). Epilogue: O1 row -> LDS, 64-MAC dot vs LDS W2, H2 written
// directly (gemm2 kernel + O1 round-trip eliminated; mechanism mega-proven).
__global__ __launch_bounds__(256) void k_gather1f(const int* __restrict__ offs,
                                                  const int* __restrict__ csr,
                                                  const float* __restrict__ dinv,
                                                  const unsigned short* __restrict__ Hs,
                                                  const float* __restrict__ b1,
                                                  const float* __restrict__ W2,
                                                  unsigned* __restrict__ H2u) {
    __shared__ float w2s[HID * OUTC];          // 8 KB
    __shared__ int   sidx[4][128];             // 2 KB (pair deg max ~70 << 128)
    __shared__ float wrow[4][2][64];           // 2 KB
    const int t = threadIdx.x;
    for (int i = t; i < HID * OUTC / 4; i += 256)
        ((float4*)w2s)[i] = ((const float4*)W2)[i];
    __syncthreads();

    const int wave = t >> 6, lane = t & 63, half = lane >> 5, c2 = lane & 31;
    const int nA = blockIdx.x * 8 + wave * 2;              // N % 8 == 0
    const int o0 = offs[nA], o1 = offs[nA + 1], o2 = offs[nA + 2];
    const int myNode = nA + half;
    const int deg = half ? (o2 - o1) : (o1 - o0);
    const int off = half ? (o1 - o0) : 0;
    const int total = o2 - o0;
    if (lane < total)      sidx[wave][lane]      = csr[o0 + lane];
    if (lane + 64 < total) sidx[wave][lane + 64] = csr[o0 + lane + 64];

    const unsigned* __restrict__ Hu = (const unsigned*)Hs; // row stride 32 dwords
    const float dn = dinv[myNode];
    unsigned su = Hu[(size_t)myNode * 32 + c2];            // self loop (pre-scaled)
    float ax0 = blo(su), ay0 = bhi(su);
    float ax1 = 0, ay1 = 0, ax2 = 0, ay2 = 0, ax3 = 0, ay3 = 0;
    const int mx = max(o1 - o0, o2 - o1);                  // wave-uniform trip
    for (int k = 0; k < mx; k += 4) {
        bool v0 = k < deg, v1 = k + 1 < deg, v2 = k + 2 < deg, v3 = k + 3 < deg;
        int s0 = v0 ? sidx[wave][off + k]     : 0;
        int s1 = v1 ? sidx[wave][off + k + 1] : 0;
        int s2 = v2 ? sidx[wave][off + k + 2] : 0;
        int s3 = v3 ? sidx[wave][off + k + 3] : 0;
        unsigned u0 = Hu[(size_t)s0 * 32 + c2];
        unsigned u1 = Hu[(size_t)s1 * 32 + c2];
        unsigned u2 = Hu[(size_t)s2 * 32 + c2];
        unsigned u3 = Hu[(size_t)s3 * 32 + c2];
        ax0 += v0 ? blo(u0) : 0.f;  ay0 += v0 ? bhi(u0) : 0.f;
        ax1 += v1 ? blo(u1) : 0.f;  ay1 += v1 ? bhi(u1) : 0.f;
        ax2 += v2 ? blo(u2) : 0.f;  ay2 += v2 ? bhi(u2) : 0.f;
        ax3 += v3 ? blo(u3) : 0.f;  ay3 += v3 ? bhi(u3) : 0.f;
    }
    float sx = (ax0 + ax1) + (ax2 + ax3);
    float sy = (ay0 + ay1) + (ay2 + ay3);
    float2 bb = *(const float2*)(b1 + 2 * c2);
    wrow[wave][half][2 * c2]     = fmaxf(sx * dn + bb.x, 0.0f);   // fused relu+bias
    wrow[wave][half][2 * c2 + 1] = fmaxf(sy * dn + bb.y, 0.0f);

    // fused gemm2: each half dots ITS node's O1 row with W2 column c2
    float acc = 0.0f;
    #pragma unroll 16
    for (int k = 0; k < HID; ++k)
        acc += wrow[wave][half][k] * w2s[k * OUTC + c2];
    float hv = acc * dn;                                   // pre-scale by dinv
    float hv1 = __shfl_down(hv, 1, 64);
    if ((c2 & 1) == 0)
        H2u[(size_t)myNode * 16 + (c2 >> 1)] =
            (unsigned)f2bf(hv) | ((unsigned)f2bf(hv1) << 16);
}

// ---------------- gather2: each QUARTER-WAVE owns a node (4 nodes/wave) ----------------
__global__ __launch_bounds__(256) void k_gather2(const int* __restrict__ offs,
                                                 const int* __restrict__ csr,
                                                 const float* __restrict__ dinv,
                                                 const unsigned* __restrict__ H2u,
                                                 const float* __restrict__ b2,
                                                 float* __restrict__ out) {
    __shared__ int sidx[4][192];               // 3 KB (quad deg max ~110 << 192)
    const int t = threadIdx.x;
    const int wave = t >> 6, lane = t & 63, q = lane >> 4, c2 = lane & 15;
    const int n0 = blockIdx.x * 16 + wave * 4;             // N % 16 == 0
    const int o0 = offs[n0],     oa = offs[n0 + 1];
    const int ob = offs[n0 + 2], oc = offs[n0 + 3], o4 = offs[n0 + 4];
    const int myNode = n0 + q;
    int deg, off;
    if (q == 0)      { deg = oa - o0; off = 0; }
    else if (q == 1) { deg = ob - oa; off = oa - o0; }
    else if (q == 2) { deg = oc - ob; off = ob - o0; }
    else             { deg = o4 - oc; off = oc - o0; }
    const int total = o4 - o0;
    if (lane < total)       sidx[wave][lane]       = csr[o0 + lane];
    if (lane + 64 < total)  sidx[wave][lane + 64]  = csr[o0 + lane + 64];
    if (lane + 128 < total) sidx[wave][lane + 128] = csr[o0 + lane + 128];

    const float dn = dinv[myNode];
    unsigned su = H2u[(size_t)myNode * 16 + c2];           // self loop (pre-scaled)
    float ax0 = blo(su), ay0 = bhi(su);
    float ax1 = 0, ay1 = 0, ax2 = 0, ay2 = 0, ax3 = 0, ay3 = 0;
    const int mx = max(max(oa - o0, ob - oa), max(oc - ob, o4 - oc));
    for (int k = 0; k < mx; k += 4) {
        bool v0 = k < deg, v1 = k + 1 < deg, v2 = k + 2 < deg, v3 = k + 3 < deg;
        int s0 = v0 ? sidx[wave][off + k]     : 0;
        int s1 = v1 ? sidx[wave][off + k + 1] : 0;
        int s2 = v2 ? sidx[wave][off + k + 2] : 0;
        int s3 = v3 ? sidx[wave][off + k + 3] : 0;
        unsigned u0 = H2u[(size_t)s0 * 16 + c2];
        unsigned u1 = H2u[(size_t)s1 * 16 + c2];
        unsigned u2 = H2u[(size_t)s2 * 16 + c2];
        unsigned u3 = H2u[(size_t)s3 * 16 + c2];
        ax0 += v0 ? blo(u0) : 0.f;  ay0 += v0 ? bhi(u0) : 0.f;
        ax1 += v1 ? blo(u1) : 0.f;  ay1 += v1 ? bhi(u1) : 0.f;
        ax2 += v2 ? blo(u2) : 0.f;  ay2 += v2 ? bhi(u2) : 0.f;
        ax3 += v3 ? blo(u3) : 0.f;  ay3 += v3 ? bhi(u3) : 0.f;
    }
    float sx = (ax0 + ax1) + (ax2 + ax3);
    float sy = (ay0 + ay1) + (ay2 + ay3);
    float2 bb = *(const float2*)(b2 + 2 * c2);
    float2 r;
    r.x = sx * dn + bb.x;
    r.y = sy * dn + bb.y;
    *(float2*)(out + (size_t)myNode * OUTC + 2 * c2) = r;  // wave-coalesced 512B
}

extern "C" void kernel_launch(void* const* d_in, const int* in_sizes, int n_in,
                              void* d_out, int out_size, void* d_ws, size_t ws_size,
                              hipStream_t stream) {
    const float* x   = (const float*)d_in[0];
    const int*   ei  = (const int*)d_in[1];
    const float* W1  = (const float*)d_in[2];
    const float* b1  = (const float*)d_in[3];
    const float* W2  = (const float*)d_in[4];
    const float* b2  = (const float*)d_in[5];
    float*       out = (float*)d_out;

    const int* srcp = ei;
    const int* dstp = ei + E;

    char* ws = (char*)d_ws;
    int*            gcnt   = (int*)(ws + 0);                   // 784 B
    int*            bbase  = (int*)(ws + 4096);                // 788 B
    int*            cursor = (int*)(ws + 8192);                // 784 B
    int*            offs   = (int*)(ws + 16384);               // 400,004 B
    float*          dinv   = (float*)(ws + (512u << 10));      // 400 KB
    unsigned*       packed = (unsigned*)(ws + (1u << 20));     // 6.4 MB (becomes csr in place)
    unsigned short* Hs     = (unsigned short*)(ws + (8u << 20));   // 12.8 MB
    unsigned*       H2u    = (unsigned*)(ws + (21u << 20));    // 6.4 MB -> ends ~27.4 MB
    int*            csr    = (int*)packed;

    hipMemsetAsync(gcnt, 0, NB * sizeof(int), stream);
    k_hist <<<256, 256, 0, stream>>>(dstp, gcnt);
    k_bscan<<<1, 256, 0, stream>>>(gcnt, bbase, cursor);
    k_part <<<PB, 256, 0, stream>>>(srcp, dstp, cursor, packed);
    k_build<<<NB, 512, 0, stream>>>(bbase, packed, offs, dinv);

    k_gemm1   <<<N / 32, 256, 0, stream>>>(x, W1, dinv, Hs);
    k_gather1f<<<N / 8,  256, 0, stream>>>(offs, csr, dinv, Hs, b1, W2, H2u);
    k_gather2 <<<N / 16, 256, 0, stream>>>(offs, csr, dinv, H2u, b2, out);
}